// Round 3
// 446.751 us; speedup vs baseline: 1.0320x; 1.0320x over previous
//
#include <hip/hip_runtime.h>

#define TDIM 256
#define BM 128
#define BK 32
#define LDST 40   // LDS row stride in bf16 elements (80 B: 16B-aligned, 2-way-max bank aliasing)
#define NSTEP 8

typedef __attribute__((ext_vector_type(4))) float f32x4;
typedef __attribute__((ext_vector_type(8))) short s16x8;

__device__ __forceinline__ unsigned short f2bf(float f) {
    union { float f; unsigned int u; } c; c.f = f;
    unsigned int u = c.u;
    u += 0x7fffu + ((u >> 16) & 1u);   // round-to-nearest-even
    return (unsigned short)(u >> 16);
}

__device__ __forceinline__ s16x8 cvt8(f32x4 v0, f32x4 v1) {
    s16x8 sv;
    sv[0] = (short)f2bf(v0[0]); sv[1] = (short)f2bf(v0[1]);
    sv[2] = (short)f2bf(v0[2]); sv[3] = (short)f2bf(v0[3]);
    sv[4] = (short)f2bf(v1[0]); sv[5] = (short)f2bf(v1[1]);
    sv[6] = (short)f2bf(v1[2]); sv[7] = (short)f2bf(v1[3]);
    return sv;
}

// Mask (j<=n) then convert: row n of W, columns jbase..jbase+7.
__device__ __forceinline__ s16x8 cvt8_mask(f32x4 v0, f32x4 v1, int jbase, int n) {
    float t[8] = {v0[0], v0[1], v0[2], v0[3], v1[0], v1[1], v1[2], v1[3]};
    s16x8 sv;
#pragma unroll
    for (int e = 0; e < 8; ++e)
        sv[e] = (short)f2bf((jbase + e) <= n ? t[e] : 0.0f);
    return sv;
}

// X: (M=262144, 256) row-major fp32; W: (256,256) row-major fp32 (row i = weights over j);
// bias: (256,) fp32; out: (M, 256) row-major fp32.
// Block computes BM x 256 output tile. Grid = M/BM = 2048.
__global__ __launch_bounds__(256, 2)
void triu_gemm_kernel(const float* __restrict__ X, const float* __restrict__ W,
                      const float* __restrict__ bias, float* __restrict__ out) {
    __shared__ __align__(16) unsigned short As[2][BM * LDST];   // 2 x 10240 B
    __shared__ __align__(16) unsigned short Bs[2][TDIM * LDST]; // 2 x 20480 B

    const int tid  = threadIdx.x;
    const int wave = tid >> 6;
    const int lane = tid & 63;
    const int quad = lane >> 4;
    const int l16  = lane & 15;
    const int wm   = wave & 1;    // 64-row slice within block tile
    const int wn   = wave >> 1;   // 128-col slice

    const long m0 = (long)blockIdx.x * BM;
    const int rr = tid >> 2;        // 0..63
    const int kq = (tid & 3) * 8;   // 0,8,16,24

    f32x4 acc[4][8];
#pragma unroll
    for (int i = 0; i < 4; ++i)
#pragma unroll
        for (int j = 0; j < 8; ++j)
            acc[i][j] = (f32x4){0.f, 0.f, 0.f, 0.f};

    f32x4 pa[2][2];   // X prefetch (fp32)
    f32x4 pw[4][2];   // W prefetch (fp32, masked at convert time)

    // ---------- prologue: stage K-tile 0 into buffer 0 ----------
#pragma unroll
    for (int p = 0; p < 2; ++p) {
        const float* src = X + (m0 + p * 64 + rr) * TDIM + kq;
        pa[p][0] = *(const f32x4*)src;
        pa[p][1] = *(const f32x4*)(src + 4);
    }
#pragma unroll
    for (int p = 0; p < 4; ++p) {
        const float* src = W + (p * 64 + rr) * TDIM + kq;
        pw[p][0] = *(const f32x4*)src;
        pw[p][1] = *(const f32x4*)(src + 4);
    }
#pragma unroll
    for (int p = 0; p < 2; ++p)
        *(s16x8*)&As[0][(p * 64 + rr) * LDST + kq] = cvt8(pa[p][0], pa[p][1]);
#pragma unroll
    for (int p = 0; p < 4; ++p)
        *(s16x8*)&Bs[0][(p * 64 + rr) * LDST + kq] =
            cvt8_mask(pw[p][0], pw[p][1], kq, p * 64 + rr);
    __syncthreads();

    // ---------- main loop: double-buffered, 1 barrier per K-step ----------
#pragma unroll
    for (int t = 0; t < NSTEP; ++t) {
        const int k0  = t * BK;
        const int k1  = k0 + BK;
        const int cur = t & 1;

        // Issue next-tile global loads FIRST; the vmcnt wait lands after the
        // MFMA phase, so HBM latency hides under frag-reads + MFMA.
        if (t < NSTEP - 1) {
#pragma unroll
            for (int p = 0; p < 2; ++p) {
                const float* src = X + (m0 + p * 64 + rr) * TDIM + (k1 + kq);
                pa[p][0] = *(const f32x4*)src;
                pa[p][1] = *(const f32x4*)(src + 4);
            }
#pragma unroll
            for (int p = 0; p < 4; ++p) {
                // Row-block p (rows p*64..p*64+63) is all-masked for K-tile at k1
                // when p*64+63 < k1 — and provably never read by a live fragment.
                if (p * 64 + 63 >= k1) {
                    const float* src = W + (p * 64 + rr) * TDIM + (k1 + kq);
                    pw[p][0] = *(const f32x4*)src;
                    pw[p][1] = *(const f32x4*)(src + 4);
                }
            }
        }

        // Triangle skip: wave's column slice [wn*128, wn*128+128) is dead once k0 >= (wn+1)*128.
        if (k0 < (wn + 1) * 128) {
            s16x8 af[4];
#pragma unroll
            for (int mi = 0; mi < 4; ++mi)
                af[mi] = *(const s16x8*)&As[cur][(wm * 64 + mi * 16 + l16) * LDST + quad * 8];
#pragma unroll
            for (int ni = 0; ni < 8; ++ni) {
                // Fragment rows [f, f+16) all have W==0 when f+15 < k0: exact-zero contribution.
                if (wn * 128 + ni * 16 + 15 >= k0) {
                    const s16x8 bf = *(const s16x8*)&Bs[cur][(wn * 128 + ni * 16 + l16) * LDST + quad * 8];
#pragma unroll
                    for (int mi = 0; mi < 4; ++mi)
                        acc[mi][ni] = __builtin_amdgcn_mfma_f32_16x16x32_bf16(
                            af[mi], bf, acc[mi][ni], 0, 0, 0);
                }
            }
        }

        // Convert + stage next tile into the other buffer; single barrier.
        if (t < NSTEP - 1) {
#pragma unroll
            for (int p = 0; p < 2; ++p)
                *(s16x8*)&As[cur ^ 1][(p * 64 + rr) * LDST + kq] = cvt8(pa[p][0], pa[p][1]);
#pragma unroll
            for (int p = 0; p < 4; ++p)
                if (p * 64 + 63 >= k1)
                    *(s16x8*)&Bs[cur ^ 1][(p * 64 + rr) * LDST + kq] =
                        cvt8_mask(pw[p][0], pw[p][1], k1 + kq, p * 64 + rr);
            __syncthreads();
        }
    }

    // ---------- epilogue: bias add + store. C/D layout: col = lane&15, row = quad*4 + reg ----------
#pragma unroll
    for (int ni = 0; ni < 8; ++ni) {
        const int n = wn * 128 + ni * 16 + l16;
        const float bv = bias[n];
#pragma unroll
        for (int mi = 0; mi < 4; ++mi) {
            const long mb = m0 + wm * 64 + mi * 16 + quad * 4;
            float* dst = out + mb * TDIM + n;
#pragma unroll
            for (int r = 0; r < 4; ++r)
                dst[(long)r * TDIM] = acc[mi][ni][r] + bv;
        }
    }
}

extern "C" void kernel_launch(void* const* d_in, const int* in_sizes, int n_in,
                              void* d_out, int out_size, void* d_ws, size_t ws_size,
                              hipStream_t stream) {
    const float* X    = (const float*)d_in[0];   // (256,1024,256) = (M=262144, 256)
    const float* W    = (const float*)d_in[1];   // (256,256)
    const float* bias = (const float*)d_in[2];   // (256,)
    float* out        = (float*)d_out;           // (M, 256)
    (void)d_ws; (void)ws_size;

    const int M = 256 * 1024;                    // B*C
    dim3 grid(M / BM);                           // 2048 blocks
    dim3 block(256);
    triu_gemm_kernel<<<grid, block, 0, stream>>>(X, W, bias, out);
}